// Round 5
// baseline (66.032 us; speedup 1.0000x reference)
//
#include <hip/hip_runtime.h>
#include <hip/hip_cooperative_groups.h>
#include <math.h>

namespace cg = cooperative_groups;

// FBPINN: out(x) = sum_k w_k(x)*subnet_k(x) / sum_k w_k(x), x scalar in [0,1].
// ONE cooperative dispatch:
//   phase 1 (blocks 0..255): tabulate numerator sum_k w_k*o_k at TBL grid
//     points. Block bx owns points [64*bx, 64*bx+64); wave j evaluates
//     candidate subnet klo_b+j (wave-uniform k -> scalar weight loads),
//     partials combined through LDS, one dense store. No atomics/zero-fill.
//   grid.sync()
//   phase 2 (all 512 blocks): float4 lerp of the numerator table; the
//     denominator is ANALYTIC (depends only on x: <=4 cosine windows).
// Lerp error ~2.5e-6 at TBL=16384, far below the 7.3e-3 threshold (and the
// harness's bf16-ULP comparison floor of 1.95e-3).

#define KSUB 16
#define NW 32
#define TBITS 14
#define TBL (1 << TBITS)      // 16384
#define SLOTS 5               // klo varies by <=1 per 64-pt stretch -> 4+1
#define CBLOCKS 512
#define CTHREADS (64 * SLOTS) // 320

// tanh(x) = 1 - 2/(exp(2x)+1); v_exp_f32 is exp2 -> scale by 2*log2(e).
static __device__ __forceinline__ float fast_tanh(float v) {
    float e = __builtin_amdgcn_exp2f(v * 2.8853900817779268f);
    return 1.0f - 2.0f * __builtin_amdgcn_rcpf(e + 1.0f);
}

// cos(pi*u), u in [0,1]: v_cos_f32 takes revolutions.
static __device__ __forceinline__ float cos_pi(float u) {
    return __builtin_amdgcn_cosf(0.5f * u);
}

static __device__ __forceinline__ float window_w(float x, int k) {
    const float invTW = 20.0f;  // 1/0.05
    float xmin = (float)k * 0.0625f - 0.06f;
    float xmax = (float)(k + 1) * 0.0625f + 0.06f;
    float up = (x - xmin + 0.025f) * invTW;
    float dn = (xmax + 0.025f - x) * invTW;
    up = fminf(fmaxf(up, 0.0f), 1.0f);
    dn = fminf(fmaxf(dn, 0.0f), 1.0f);
    return 0.25f * (1.0f - cos_pi(up)) * (1.0f - cos_pi(dn));
}

// Active subnets at x: k in (16x-2.36, 16x+1.36); klo..klo+3 always covers.
static __device__ __forceinline__ float den_analytic(float xv) {
    int klo = (int)ceilf(16.0f * xv - 2.36f);
    float den = 0.f;
#pragma unroll
    for (int j = 0; j < 4; ++j) {
        int k = klo + j;
        if (k >= 0 && k < KSUB) den += window_w(xv, k);
    }
    return den;
}

// MLP 1->32->32->32->1 with tanh. Pointers wave-uniform -> s_load streams.
static __device__ __forceinline__ float subnet_eval(
    float xn,
    const float* __restrict__ w0, const float* __restrict__ bb0,
    const float* __restrict__ w1, const float* __restrict__ bb1,
    const float* __restrict__ w2, const float* __restrict__ bb2,
    const float* __restrict__ w3, float bb3)
{
    float h0[NW], h1[NW];
#pragma unroll
    for (int o = 0; o < NW; ++o) h0[o] = fast_tanh(fmaf(w0[o], xn, bb0[o]));
#pragma unroll
    for (int o = 0; o < NW; ++o) {
        float a0 = bb1[o], a1 = 0.f, a2 = 0.f, a3 = 0.f;
        const float* row = &w1[o * NW];
#pragma unroll
        for (int j = 0; j < NW; j += 4) {
            a0 = fmaf(row[j + 0], h0[j + 0], a0);
            a1 = fmaf(row[j + 1], h0[j + 1], a1);
            a2 = fmaf(row[j + 2], h0[j + 2], a2);
            a3 = fmaf(row[j + 3], h0[j + 3], a3);
        }
        h1[o] = fast_tanh((a0 + a1) + (a2 + a3));
    }
#pragma unroll
    for (int o = 0; o < NW; ++o) {
        float a0 = bb2[o], a1 = 0.f, a2 = 0.f, a3 = 0.f;
        const float* row = &w2[o * NW];
#pragma unroll
        for (int j = 0; j < NW; j += 4) {
            a0 = fmaf(row[j + 0], h1[j + 0], a0);
            a1 = fmaf(row[j + 1], h1[j + 1], a1);
            a2 = fmaf(row[j + 2], h1[j + 2], a2);
            a3 = fmaf(row[j + 3], h1[j + 3], a3);
        }
        h0[o] = fast_tanh((a0 + a1) + (a2 + a3));  // reuse h0 as h2
    }
    float a0 = bb3, a1 = 0.f, a2 = 0.f, a3 = 0.f;
#pragma unroll
    for (int j = 0; j < NW; j += 4) {
        a0 = fmaf(w3[j + 0], h0[j + 0], a0);
        a1 = fmaf(w3[j + 1], h0[j + 1], a1);
        a2 = fmaf(w3[j + 2], h0[j + 2], a2);
        a3 = fmaf(w3[j + 3], h0[j + 3], a3);
    }
    return (a0 + a1) + (a2 + a3);
}

__global__ __launch_bounds__(CTHREADS) void fused_build_eval(
    const float* __restrict__ W0, const float* __restrict__ B0,
    const float* __restrict__ W1, const float* __restrict__ B1,
    const float* __restrict__ W2, const float* __restrict__ B2,
    const float* __restrict__ W3, const float* __restrict__ B3,
    const float* __restrict__ x, float* __restrict__ gnum,
    float* __restrict__ out, int N)
{
    __shared__ float part[SLOTS][64];

    // ---- phase 1: build (blocks 0..TBL/64-1); NO early returns ----
    if (blockIdx.x < TBL / 64) {
        const int lane = threadIdx.x & 63;
        const int wave = threadIdx.x >> 6;
        const int i = blockIdx.x * 64 + lane;
        const float inv = 1.0f / (float)(TBL - 1);
        const float xg = (float)i * inv;

        float x_lo = (float)(blockIdx.x * 64) * inv;
        int klo_b = (int)ceilf(16.0f * x_lo - 2.36f);
        int k = __builtin_amdgcn_readfirstlane(klo_b + wave);  // wave-uniform

        float val = 0.0f;
        if (k >= 0 && k < KSUB) {
            float w = window_w(xg, k);
            if (__ballot(w > 0.0f)) {  // wave-uniform branch
                float xmin = (float)k * 0.0625f - 0.06f;
                float xmax = (float)(k + 1) * 0.0625f + 0.06f;
                float center = 0.5f * (xmin + xmax);
                float scale = fmaxf(0.5f * (xmax - xmin), 1e-9f);
                float xn = (xg - center) / scale;
                float o = subnet_eval(xn, &W0[k * NW], &B0[k * NW],
                                      &W1[k * NW * NW], &B1[k * NW],
                                      &W2[k * NW * NW], &B2[k * NW],
                                      &W3[k * NW], B3[k]);
                val = w * o;
            }
        }
        part[wave][lane] = val;
        __syncthreads();
        if (threadIdx.x < 64) {
            float s = part[0][lane];
#pragma unroll
            for (int j = 1; j < SLOTS; ++j) s += part[j][lane];
            gnum[i] = s;
        }
    }

    cg::this_grid().sync();

    // ---- phase 2: eval (all blocks), float4 grid-stride ----
    const float scaleT = (float)(TBL - 1);
    const int nthreads = CBLOCKS * CTHREADS;
    int tid = blockIdx.x * CTHREADS + threadIdx.x;
    for (int base = tid * 4; base < N; base += nthreads * 4) {
        if (base + 3 < N) {
            float4 xv = *reinterpret_cast<const float4*>(&x[base]);
            float4 r;
            float* rp = &r.x;
            const float* xp = &xv.x;
#pragma unroll
            for (int j = 0; j < 4; ++j) {
                float xj = xp[j];
                float t = fminf(fmaxf(xj * scaleT, 0.0f), scaleT);
                int i0 = (int)t;
                if (i0 > TBL - 2) i0 = TBL - 2;
                float f = t - (float)i0;
                float n0 = gnum[i0], n1 = gnum[i0 + 1];
                float num = fmaf(f, n1 - n0, n0);
                float den = den_analytic(xj);
                rp[j] = num * __builtin_amdgcn_rcpf(den + 1e-12f);
            }
            *reinterpret_cast<float4*>(&out[base]) = r;
        } else {
            for (int j = base; j < N; ++j) {
                float xj = x[j];
                float t = fminf(fmaxf(xj * scaleT, 0.0f), scaleT);
                int i0 = (int)t;
                if (i0 > TBL - 2) i0 = TBL - 2;
                float f = t - (float)i0;
                float num = fmaf(f, gnum[i0 + 1] - gnum[i0], gnum[i0]);
                float den = den_analytic(xj);
                out[j] = num * __builtin_amdgcn_rcpf(den + 1e-12f);
            }
        }
    }
}

// ---- fallback 2-kernel path (used only if cooperative launch errors) ----
__global__ __launch_bounds__(CTHREADS) void build_tables(
    const float* __restrict__ W0, const float* __restrict__ B0,
    const float* __restrict__ W1, const float* __restrict__ B1,
    const float* __restrict__ W2, const float* __restrict__ B2,
    const float* __restrict__ W3, const float* __restrict__ B3,
    float* __restrict__ gnum)
{
    __shared__ float part[SLOTS][64];
    const int lane = threadIdx.x & 63;
    const int wave = threadIdx.x >> 6;
    const int i = blockIdx.x * 64 + lane;
    const float inv = 1.0f / (float)(TBL - 1);
    const float xg = (float)i * inv;

    float x_lo = (float)(blockIdx.x * 64) * inv;
    int klo_b = (int)ceilf(16.0f * x_lo - 2.36f);
    int k = __builtin_amdgcn_readfirstlane(klo_b + wave);

    float val = 0.0f;
    if (k >= 0 && k < KSUB) {
        float w = window_w(xg, k);
        if (__ballot(w > 0.0f)) {
            float xmin = (float)k * 0.0625f - 0.06f;
            float xmax = (float)(k + 1) * 0.0625f + 0.06f;
            float center = 0.5f * (xmin + xmax);
            float scale = fmaxf(0.5f * (xmax - xmin), 1e-9f);
            float xn = (xg - center) / scale;
            float o = subnet_eval(xn, &W0[k * NW], &B0[k * NW],
                                  &W1[k * NW * NW], &B1[k * NW],
                                  &W2[k * NW * NW], &B2[k * NW],
                                  &W3[k * NW], B3[k]);
            val = w * o;
        }
    }
    part[wave][lane] = val;
    __syncthreads();
    if (threadIdx.x < 64) {
        float s = part[0][lane];
#pragma unroll
        for (int j = 1; j < SLOTS; ++j) s += part[j][lane];
        gnum[i] = s;
    }
}

__global__ void eval_lerp(const float* __restrict__ x,
                          const float* __restrict__ gnum,
                          float* __restrict__ out, int N)
{
    const float scaleT = (float)(TBL - 1);
    int idx = blockIdx.x * blockDim.x + threadIdx.x;
    int base = idx * 4;
    if (base + 3 < N) {
        float4 xv = *reinterpret_cast<const float4*>(&x[base]);
        float4 r;
        float* rp = &r.x;
        const float* xp = &xv.x;
#pragma unroll
        for (int j = 0; j < 4; ++j) {
            float xj = xp[j];
            float t = fminf(fmaxf(xj * scaleT, 0.0f), scaleT);
            int i0 = (int)t;
            if (i0 > TBL - 2) i0 = TBL - 2;
            float f = t - (float)i0;
            float n0 = gnum[i0], n1 = gnum[i0 + 1];
            float num = fmaf(f, n1 - n0, n0);
            float den = den_analytic(xj);
            rp[j] = num * __builtin_amdgcn_rcpf(den + 1e-12f);
        }
        *reinterpret_cast<float4*>(&out[base]) = r;
    } else {
        for (int j = base; j < N; ++j) {
            float xj = x[j];
            float t = fminf(fmaxf(xj * scaleT, 0.0f), scaleT);
            int i0 = (int)t;
            if (i0 > TBL - 2) i0 = TBL - 2;
            float f = t - (float)i0;
            float num = fmaf(f, gnum[i0 + 1] - gnum[i0], gnum[i0]);
            float den = den_analytic(xj);
            out[j] = num * __builtin_amdgcn_rcpf(den + 1e-12f);
        }
    }
}

extern "C" void kernel_launch(void* const* d_in, const int* in_sizes, int n_in,
                              void* d_out, int out_size, void* d_ws, size_t ws_size,
                              hipStream_t stream) {
    const float* x  = (const float*)d_in[0];
    const float* W0 = (const float*)d_in[1];
    const float* B0 = (const float*)d_in[2];
    const float* W1 = (const float*)d_in[3];
    const float* B1 = (const float*)d_in[4];
    const float* W2 = (const float*)d_in[5];
    const float* B2 = (const float*)d_in[6];
    const float* W3 = (const float*)d_in[7];
    const float* B3 = (const float*)d_in[8];
    float* out = (float*)d_out;
    int N = in_sizes[0];
    float* gnum = (float*)d_ws;

    void* args[] = {
        (void*)&W0, (void*)&B0, (void*)&W1, (void*)&B1,
        (void*)&W2, (void*)&B2, (void*)&W3, (void*)&B3,
        (void*)&x, (void*)&gnum, (void*)&out, (void*)&N
    };
    hipError_t err = hipLaunchCooperativeKernel(
        (const void*)fused_build_eval, dim3(CBLOCKS), dim3(CTHREADS),
        args, 0, stream);

    if (err != hipSuccess) {
        (void)hipGetLastError();  // clear
        build_tables<<<TBL / 64, CTHREADS, 0, stream>>>(
            W0, B0, W1, B1, W2, B2, W3, B3, gnum);
        int nv = (N + 3) / 4;
        eval_lerp<<<(nv + 255) / 256, 256, 0, stream>>>(x, gnum, out, N);
    }
}

// Round 6
// 43.128 us; speedup vs baseline: 1.5311x; 1.5311x over previous
//
#include <hip/hip_runtime.h>
#include <math.h>

// FBPINN: out(x) = sum_k w_k(x)*subnet_k(x) / sum_k w_k(x), x scalar in [0,1].
// ONE cooperative dispatch, manual L3-only barrier (cg::grid.sync costs ~60us
// on MI355X due to per-block L2 maintenance; measured R5):
//   phase 1 (blocks 0..255): build numerator table sum_k w_k*o_k at TBL pts.
//     Block bx owns pts [64*bx,64*bx+64); wave j (4 waves) evaluates subnet
//     klo_b+j (wave-uniform -> scalar weight loads). For a 64-pt stretch,
//     klo varies by <=1 and subnet klo_b+4 is never active (margin 0.28/16 >
//     stretch span 0.0615/16*16), so 4 slots suffice. Table stores are
//     agent-scope relaxed atomics -> land in the SHARED L3 (bypass XCD L2).
//   barrier: per-block MAGIC slot (atomic store after s_waitcnt vmcnt(0));
//     all blocks spin on the 256 slots with relaxed atomic loads. All shared
//     data flows strictly through L3 => no fences/flushes needed.
//     Replay-safe: leftover MAGIC slots let replays skip the wait and read
//     table values that this replay rewrites with identical data (benign).
//   phase 2 (all 512 blocks): float4 lerp of the table (atomic loads);
//     denominator is ANALYTIC (<=4 cosine windows of x only).
// Lerp error ~2.5e-6 at TBL=16384 << 7.3e-3 threshold (bf16 floor 1.95e-3).

#define KSUB 16
#define NW 32
#define TBITS 14
#define TBL (1 << TBITS)      // 16384
#define SLOTS 4
#define CBLOCKS 512
#define CTHREADS 256
#define NBUILD (TBL / 64)     // 256 builder blocks
#define MAGIC 0x5EEDF00Du

// tanh(x) = 1 - 2/(exp(2x)+1); v_exp_f32 is exp2 -> scale by 2*log2(e).
static __device__ __forceinline__ float fast_tanh(float v) {
    float e = __builtin_amdgcn_exp2f(v * 2.8853900817779268f);
    return 1.0f - 2.0f * __builtin_amdgcn_rcpf(e + 1.0f);
}

// cos(pi*u), u in [0,1]: v_cos_f32 takes revolutions.
static __device__ __forceinline__ float cos_pi(float u) {
    return __builtin_amdgcn_cosf(0.5f * u);
}

static __device__ __forceinline__ float window_w(float x, int k) {
    const float invTW = 20.0f;  // 1/0.05
    float xmin = (float)k * 0.0625f - 0.06f;
    float xmax = (float)(k + 1) * 0.0625f + 0.06f;
    float up = (x - xmin + 0.025f) * invTW;
    float dn = (xmax + 0.025f - x) * invTW;
    up = fminf(fmaxf(up, 0.0f), 1.0f);
    dn = fminf(fmaxf(dn, 0.0f), 1.0f);
    return 0.25f * (1.0f - cos_pi(up)) * (1.0f - cos_pi(dn));
}

// Active subnets at x: k in (16x-2.36, 16x+1.36) => at most 4, klo..klo+3.
static __device__ __forceinline__ float den_analytic(float xv) {
    int klo = (int)ceilf(16.0f * xv - 2.36f);
    float den = 0.f;
#pragma unroll
    for (int j = 0; j < 4; ++j) {
        int k = klo + j;
        if (k >= 0 && k < KSUB) den += window_w(xv, k);
    }
    return den;
}

// MLP 1->32->32->32->1 with tanh. Pointers wave-uniform -> s_load streams.
static __device__ __forceinline__ float subnet_eval(
    float xn,
    const float* __restrict__ w0, const float* __restrict__ bb0,
    const float* __restrict__ w1, const float* __restrict__ bb1,
    const float* __restrict__ w2, const float* __restrict__ bb2,
    const float* __restrict__ w3, float bb3)
{
    float h0[NW], h1[NW];
#pragma unroll
    for (int o = 0; o < NW; ++o) h0[o] = fast_tanh(fmaf(w0[o], xn, bb0[o]));
#pragma unroll
    for (int o = 0; o < NW; ++o) {
        float a0 = bb1[o], a1 = 0.f, a2 = 0.f, a3 = 0.f;
        const float* row = &w1[o * NW];
#pragma unroll
        for (int j = 0; j < NW; j += 4) {
            a0 = fmaf(row[j + 0], h0[j + 0], a0);
            a1 = fmaf(row[j + 1], h0[j + 1], a1);
            a2 = fmaf(row[j + 2], h0[j + 2], a2);
            a3 = fmaf(row[j + 3], h0[j + 3], a3);
        }
        h1[o] = fast_tanh((a0 + a1) + (a2 + a3));
    }
#pragma unroll
    for (int o = 0; o < NW; ++o) {
        float a0 = bb2[o], a1 = 0.f, a2 = 0.f, a3 = 0.f;
        const float* row = &w2[o * NW];
#pragma unroll
        for (int j = 0; j < NW; j += 4) {
            a0 = fmaf(row[j + 0], h1[j + 0], a0);
            a1 = fmaf(row[j + 1], h1[j + 1], a1);
            a2 = fmaf(row[j + 2], h1[j + 2], a2);
            a3 = fmaf(row[j + 3], h1[j + 3], a3);
        }
        h0[o] = fast_tanh((a0 + a1) + (a2 + a3));  // reuse h0 as h2
    }
    float a0 = bb3, a1 = 0.f, a2 = 0.f, a3 = 0.f;
#pragma unroll
    for (int j = 0; j < NW; j += 4) {
        a0 = fmaf(w3[j + 0], h0[j + 0], a0);
        a1 = fmaf(w3[j + 1], h0[j + 1], a1);
        a2 = fmaf(w3[j + 2], h0[j + 2], a2);
        a3 = fmaf(w3[j + 3], h0[j + 3], a3);
    }
    return (a0 + a1) + (a2 + a3);
}

// Per-block build of one 64-pt stretch: returns lane's summed numerator value
// (valid for threadIdx.x < 64 after the __syncthreads inside).
static __device__ __forceinline__ float build_stretch(
    int bx, float* part /* [SLOTS][64] */,
    const float* __restrict__ W0, const float* __restrict__ B0,
    const float* __restrict__ W1, const float* __restrict__ B1,
    const float* __restrict__ W2, const float* __restrict__ B2,
    const float* __restrict__ W3, const float* __restrict__ B3)
{
    const int lane = threadIdx.x & 63;
    const int wave = threadIdx.x >> 6;
    const int i = bx * 64 + lane;
    const float inv = 1.0f / (float)(TBL - 1);
    const float xg = (float)i * inv;

    float x_lo = (float)(bx * 64) * inv;
    int klo_b = (int)ceilf(16.0f * x_lo - 2.36f);
    int k = __builtin_amdgcn_readfirstlane(klo_b + wave);  // wave-uniform

    float val = 0.0f;
    if (k >= 0 && k < KSUB) {
        float w = window_w(xg, k);
        if (__ballot(w > 0.0f)) {  // wave-uniform branch
            float xmin = (float)k * 0.0625f - 0.06f;
            float xmax = (float)(k + 1) * 0.0625f + 0.06f;
            float center = 0.5f * (xmin + xmax);
            float scale = fmaxf(0.5f * (xmax - xmin), 1e-9f);
            float xn = (xg - center) / scale;
            float o = subnet_eval(xn, &W0[k * NW], &B0[k * NW],
                                  &W1[k * NW * NW], &B1[k * NW],
                                  &W2[k * NW * NW], &B2[k * NW],
                                  &W3[k * NW], B3[k]);
            val = w * o;
        }
    }
    part[wave * 64 + lane] = val;
    __syncthreads();
    float s = 0.0f;
    if (threadIdx.x < 64) {
        s = part[lane];
#pragma unroll
        for (int j = 1; j < SLOTS; ++j) s += part[j * 64 + lane];
    }
    return s;
}

static __device__ __forceinline__ float eval_point(
    float xj, const unsigned* __restrict__ gnum_u)
{
    const float scaleT = (float)(TBL - 1);
    float t = fminf(fmaxf(xj * scaleT, 0.0f), scaleT);
    int i0 = (int)t;
    if (i0 > TBL - 2) i0 = TBL - 2;
    float f = t - (float)i0;
    float n0 = __uint_as_float(__hip_atomic_load(
        &gnum_u[i0], __ATOMIC_RELAXED, __HIP_MEMORY_SCOPE_AGENT));
    float n1 = __uint_as_float(__hip_atomic_load(
        &gnum_u[i0 + 1], __ATOMIC_RELAXED, __HIP_MEMORY_SCOPE_AGENT));
    float num = fmaf(f, n1 - n0, n0);
    float den = den_analytic(xj);
    return num * __builtin_amdgcn_rcpf(den + 1e-12f);
}

__global__ __launch_bounds__(CTHREADS) void fused_build_eval(
    const float* __restrict__ W0, const float* __restrict__ B0,
    const float* __restrict__ W1, const float* __restrict__ B1,
    const float* __restrict__ W2, const float* __restrict__ B2,
    const float* __restrict__ W3, const float* __restrict__ B3,
    const float* __restrict__ x, unsigned* __restrict__ gnum_u,
    unsigned* __restrict__ slots, float* __restrict__ out, int N)
{
    __shared__ float part[SLOTS * 64];

    // ---- phase 1: build ----
    if (blockIdx.x < NBUILD) {
        float s = build_stretch(blockIdx.x, part, W0, B0, W1, B1, W2, B2, W3, B3);
        if (threadIdx.x < 64) {
            // table store -> L3 (agent scope, bypasses XCD L2)
            __hip_atomic_store(&gnum_u[blockIdx.x * 64 + (threadIdx.x & 63)],
                               __float_as_uint(s),
                               __ATOMIC_RELAXED, __HIP_MEMORY_SCOPE_AGENT);
            // order: table stores complete at L3 before the slot flips
            asm volatile("s_waitcnt vmcnt(0)" ::: "memory");
            if (threadIdx.x == 0)
                __hip_atomic_store(&slots[blockIdx.x], MAGIC,
                                   __ATOMIC_RELAXED, __HIP_MEMORY_SCOPE_AGENT);
        }
    }

    // ---- barrier: wait for all NBUILD slots == MAGIC (wave 0 polls) ----
    if (threadIdx.x < 64) {
        const int b = (threadIdx.x & 63) * 4;
        for (;;) {
            unsigned a0 = __hip_atomic_load(&slots[b + 0], __ATOMIC_RELAXED,
                                            __HIP_MEMORY_SCOPE_AGENT);
            unsigned a1 = __hip_atomic_load(&slots[b + 1], __ATOMIC_RELAXED,
                                            __HIP_MEMORY_SCOPE_AGENT);
            unsigned a2 = __hip_atomic_load(&slots[b + 2], __ATOMIC_RELAXED,
                                            __HIP_MEMORY_SCOPE_AGENT);
            unsigned a3 = __hip_atomic_load(&slots[b + 3], __ATOMIC_RELAXED,
                                            __HIP_MEMORY_SCOPE_AGENT);
            bool ok = (a0 == MAGIC) & (a1 == MAGIC) & (a2 == MAGIC) & (a3 == MAGIC);
            if (__all(ok)) break;
            __builtin_amdgcn_s_sleep(4);
        }
    }
    __syncthreads();

    // ---- phase 2: eval, float4 grid-stride ----
    const int nthreads = CBLOCKS * CTHREADS;
    int tid = blockIdx.x * CTHREADS + threadIdx.x;
    for (int base = tid * 4; base < N; base += nthreads * 4) {
        if (base + 3 < N) {
            float4 xv = *reinterpret_cast<const float4*>(&x[base]);
            float4 r;
            r.x = eval_point(xv.x, gnum_u);
            r.y = eval_point(xv.y, gnum_u);
            r.z = eval_point(xv.z, gnum_u);
            r.w = eval_point(xv.w, gnum_u);
            *reinterpret_cast<float4*>(&out[base]) = r;
        } else {
            for (int j = base; j < N; ++j) out[j] = eval_point(x[j], gnum_u);
        }
    }
}

// ---- fallback 2-kernel path (used only if cooperative launch errors) ----
__global__ __launch_bounds__(CTHREADS) void build_tables(
    const float* __restrict__ W0, const float* __restrict__ B0,
    const float* __restrict__ W1, const float* __restrict__ B1,
    const float* __restrict__ W2, const float* __restrict__ B2,
    const float* __restrict__ W3, const float* __restrict__ B3,
    float* __restrict__ gnum)
{
    __shared__ float part[SLOTS * 64];
    float s = build_stretch(blockIdx.x, part, W0, B0, W1, B1, W2, B2, W3, B3);
    if (threadIdx.x < 64) gnum[blockIdx.x * 64 + (threadIdx.x & 63)] = s;
}

__global__ void eval_lerp(const float* __restrict__ x,
                          const float* __restrict__ gnum,
                          float* __restrict__ out, int N)
{
    const float scaleT = (float)(TBL - 1);
    int idx = blockIdx.x * blockDim.x + threadIdx.x;
    int base = idx * 4;
    if (base + 3 < N) {
        float4 xv = *reinterpret_cast<const float4*>(&x[base]);
        float4 r;
        float* rp = &r.x;
        const float* xp = &xv.x;
#pragma unroll
        for (int j = 0; j < 4; ++j) {
            float xj = xp[j];
            float t = fminf(fmaxf(xj * scaleT, 0.0f), scaleT);
            int i0 = (int)t;
            if (i0 > TBL - 2) i0 = TBL - 2;
            float f = t - (float)i0;
            float num = fmaf(f, gnum[i0 + 1] - gnum[i0], gnum[i0]);
            float den = den_analytic(xj);
            rp[j] = num * __builtin_amdgcn_rcpf(den + 1e-12f);
        }
        *reinterpret_cast<float4*>(&out[base]) = r;
    } else {
        for (int j = base; j < N; ++j) {
            float xj = x[j];
            float t = fminf(fmaxf(xj * scaleT, 0.0f), scaleT);
            int i0 = (int)t;
            if (i0 > TBL - 2) i0 = TBL - 2;
            float f = t - (float)i0;
            float num = fmaf(f, gnum[i0 + 1] - gnum[i0], gnum[i0]);
            float den = den_analytic(xj);
            out[j] = num * __builtin_amdgcn_rcpf(den + 1e-12f);
        }
    }
}

extern "C" void kernel_launch(void* const* d_in, const int* in_sizes, int n_in,
                              void* d_out, int out_size, void* d_ws, size_t ws_size,
                              hipStream_t stream) {
    const float* x  = (const float*)d_in[0];
    const float* W0 = (const float*)d_in[1];
    const float* B0 = (const float*)d_in[2];
    const float* W1 = (const float*)d_in[3];
    const float* B1 = (const float*)d_in[4];
    const float* W2 = (const float*)d_in[5];
    const float* B2 = (const float*)d_in[6];
    const float* W3 = (const float*)d_in[7];
    const float* B3 = (const float*)d_in[8];
    float* out = (float*)d_out;
    int N = in_sizes[0];

    unsigned* gnum_u = (unsigned*)d_ws;
    unsigned* slots  = gnum_u + TBL;

    void* args[] = {
        (void*)&W0, (void*)&B0, (void*)&W1, (void*)&B1,
        (void*)&W2, (void*)&B2, (void*)&W3, (void*)&B3,
        (void*)&x, (void*)&gnum_u, (void*)&slots, (void*)&out, (void*)&N
    };
    hipError_t err = hipLaunchCooperativeKernel(
        (const void*)fused_build_eval, dim3(CBLOCKS), dim3(CTHREADS),
        args, 0, stream);

    if (err != hipSuccess) {
        (void)hipGetLastError();  // clear
        float* gnum_f = (float*)d_ws;
        build_tables<<<NBUILD, CTHREADS, 0, stream>>>(
            W0, B0, W1, B1, W2, B2, W3, B3, gnum_f);
        int nv = (N + 3) / 4;
        eval_lerp<<<(nv + 255) / 256, 256, 0, stream>>>(x, gnum_f, out, N);
    }
}

// Round 7
// 26.645 us; speedup vs baseline: 2.4782x; 1.6186x over previous
//
#include <hip/hip_runtime.h>
#include <math.h>

// FBPINN: out(x) = sum_k w_k(x)*subnet_k(x) / sum_k w_k(x), x scalar in [0,1].
// Two dispatches (fusion abandoned: cg::grid.sync = ~60us, manual L3 barrier
// = ~33us on MI355X — both dwarf the ~4us node they save; measured R5/R6):
//  1) build_tables: numerator table sum_k w_k*o_k at TBL grid points.
//     Block = 512 threads (8 waves) per 64-pt stretch. Wave (slot,half):
//     subnet k = klo_b + slot (wave-uniform -> scalar s_load weight streams),
//     computes HALF of layers 1/2's outputs; full activations exchanged via
//     LDS hx[slot][o][lane] (lane-contiguous -> conflict-free). 2048 waves =
//     2 waves/SIMD so s_load + transcendental latency is hidden (the R4
//     structure was 1 wave/SIMD and latency-bound at ~12us).
//  2) eval_lerp: float4 lerp of the table; denominator is ANALYTIC
//     (depends only on x: <=4 cosine windows). Kernel-boundary coherence
//     makes plain loads/stores safe (R1-R4 validated).
// Lerp error ~2.5e-6 at TBL=16384 << 7.3e-3 threshold (bf16 floor 1.95e-3).

#define KSUB 16
#define NW 32
#define TBL 16384
#define SLOTS 4          // open interval of active k has width 3.78 over a
                         // stretch -> at most 4 integers, klo_b..klo_b+3
#define BTHREADS 512     // 8 waves: slot = wid&3, half = wid>>2

// tanh(x) = 1 - 2/(exp(2x)+1); v_exp_f32 is exp2 -> scale by 2*log2(e).
static __device__ __forceinline__ float fast_tanh(float v) {
    float e = __builtin_amdgcn_exp2f(v * 2.8853900817779268f);
    return 1.0f - 2.0f * __builtin_amdgcn_rcpf(e + 1.0f);
}

// cos(pi*u), u in [0,1]: v_cos_f32 takes revolutions.
static __device__ __forceinline__ float cos_pi(float u) {
    return __builtin_amdgcn_cosf(0.5f * u);
}

static __device__ __forceinline__ float window_w(float x, int k) {
    const float invTW = 20.0f;  // 1/0.05
    float xmin = (float)k * 0.0625f - 0.06f;
    float xmax = (float)(k + 1) * 0.0625f + 0.06f;
    float up = (x - xmin + 0.025f) * invTW;
    float dn = (xmax + 0.025f - x) * invTW;
    up = fminf(fmaxf(up, 0.0f), 1.0f);
    dn = fminf(fmaxf(dn, 0.0f), 1.0f);
    return 0.25f * (1.0f - cos_pi(up)) * (1.0f - cos_pi(dn));
}

// Active subnets at x: k in (16x-2.36, 16x+1.36) => at most 4, klo..klo+3.
static __device__ __forceinline__ float den_analytic(float xv) {
    int klo = (int)ceilf(16.0f * xv - 2.36f);
    float den = 0.f;
#pragma unroll
    for (int j = 0; j < 4; ++j) {
        int k = klo + j;
        if (k >= 0 && k < KSUB) den += window_w(xv, k);
    }
    return den;
}

// grid = TBL/64 blocks x 512 threads. Split-output build (see header).
__global__ __launch_bounds__(BTHREADS) void build_tables(
    const float* __restrict__ W0, const float* __restrict__ B0,
    const float* __restrict__ W1, const float* __restrict__ B1,
    const float* __restrict__ W2, const float* __restrict__ B2,
    const float* __restrict__ W3, const float* __restrict__ B3,
    float* __restrict__ gnum)
{
    __shared__ float hx[SLOTS][NW][64];   // 32 KB activation exchange
    __shared__ float part[SLOTS][64];

    const int lane = threadIdx.x & 63;
    const int wid  = threadIdx.x >> 6;
    const int slot = wid & 3;
    const int half = wid >> 2;
    const int bx   = blockIdx.x;
    const int i    = bx * 64 + lane;
    const float inv = 1.0f / (float)(TBL - 1);
    const float xg  = (float)i * inv;

    float x_lo = (float)(bx * 64) * inv;
    int klo_b = (int)ceilf(16.0f * x_lo - 2.36f);
    int k  = __builtin_amdgcn_readfirstlane(klo_b + slot);  // wave-uniform
    int kc = min(max(k, 0), KSUB - 1);
    const bool active = (k >= 0) && (k < KSUB);

    // xn: scale is constant 0.09125 for every subnet
    const float INVS = 10.958904109589041f;  // 1/0.09125
    float center = ((float)kc + 0.5f) * 0.0625f;  // (xmin+xmax)/2
    float xn = (xg - center) * INVS;

    float h[NW];
    // layer 0 (full, cheap, per lane)
    {
        const float* w0 = &W0[kc * NW];
        const float* b0 = &B0[kc * NW];
#pragma unroll
        for (int o = 0; o < NW; ++o) h[o] = fast_tanh(fmaf(w0[o], xn, b0[o]));
    }
    // layer 1: this wave computes outputs [half*16, half*16+16)
    {
        const float* w1 = &W1[kc * NW * NW];
        const float* b1 = &B1[kc * NW];
        float hh[16];
#pragma unroll
        for (int oo = 0; oo < 16; ++oo) {
            const int o = half * 16 + oo;
            const float* row = &w1[o * NW];
            float a0 = b1[o], a1 = 0.f, a2 = 0.f, a3 = 0.f;
#pragma unroll
            for (int j = 0; j < NW; j += 4) {
                a0 = fmaf(row[j + 0], h[j + 0], a0);
                a1 = fmaf(row[j + 1], h[j + 1], a1);
                a2 = fmaf(row[j + 2], h[j + 2], a2);
                a3 = fmaf(row[j + 3], h[j + 3], a3);
            }
            hh[oo] = fast_tanh((a0 + a1) + (a2 + a3));
        }
#pragma unroll
        for (int oo = 0; oo < 16; ++oo) hx[slot][half * 16 + oo][lane] = hh[oo];
    }
    __syncthreads();
#pragma unroll
    for (int o = 0; o < NW; ++o) h[o] = hx[slot][o][lane];  // full h1
    __syncthreads();  // all reads done before hx is overwritten

    // layer 2: same split
    {
        const float* w2 = &W2[kc * NW * NW];
        const float* b2 = &B2[kc * NW];
        float hh[16];
#pragma unroll
        for (int oo = 0; oo < 16; ++oo) {
            const int o = half * 16 + oo;
            const float* row = &w2[o * NW];
            float a0 = b2[o], a1 = 0.f, a2 = 0.f, a3 = 0.f;
#pragma unroll
            for (int j = 0; j < NW; j += 4) {
                a0 = fmaf(row[j + 0], h[j + 0], a0);
                a1 = fmaf(row[j + 1], h[j + 1], a1);
                a2 = fmaf(row[j + 2], h[j + 2], a2);
                a3 = fmaf(row[j + 3], h[j + 3], a3);
            }
            hh[oo] = fast_tanh((a0 + a1) + (a2 + a3));
        }
#pragma unroll
        for (int oo = 0; oo < 16; ++oo) hx[slot][half * 16 + oo][lane] = hh[oo];
    }
    __syncthreads();

    // layer 3 + window: half-0 waves only
    if (half == 0) {
#pragma unroll
        for (int o = 0; o < NW; ++o) h[o] = hx[slot][o][lane];  // full h2
        const float* w3 = &W3[kc * NW];
        float a0 = B3[kc], a1 = 0.f, a2 = 0.f, a3 = 0.f;
#pragma unroll
        for (int j = 0; j < NW; j += 4) {
            a0 = fmaf(w3[j + 0], h[j + 0], a0);
            a1 = fmaf(w3[j + 1], h[j + 1], a1);
            a2 = fmaf(w3[j + 2], h[j + 2], a2);
            a3 = fmaf(w3[j + 3], h[j + 3], a3);
        }
        float o = (a0 + a1) + (a2 + a3);
        float w = window_w(xg, kc);
        part[slot][lane] = (active && w > 0.0f) ? w * o : 0.0f;
    }
    __syncthreads();
    if (threadIdx.x < 64) {
        gnum[i] = (part[0][lane] + part[1][lane]) +
                  (part[2][lane] + part[3][lane]);
    }
}

// Lerp the numerator table; denominator computed analytically per point.
__global__ void eval_lerp(const float* __restrict__ x,
                          const float* __restrict__ gnum,
                          float* __restrict__ out, int N)
{
    const float scaleT = (float)(TBL - 1);
    int idx = blockIdx.x * blockDim.x + threadIdx.x;
    int base = idx * 4;
    if (base + 3 < N) {
        float4 xv = *reinterpret_cast<const float4*>(&x[base]);
        float4 r;
        float* rp = &r.x;
        const float* xp = &xv.x;
#pragma unroll
        for (int j = 0; j < 4; ++j) {
            float xj = xp[j];
            float t = fminf(fmaxf(xj * scaleT, 0.0f), scaleT);
            int i0 = (int)t;
            if (i0 > TBL - 2) i0 = TBL - 2;
            float f = t - (float)i0;
            float n0 = gnum[i0], n1 = gnum[i0 + 1];
            float num = fmaf(f, n1 - n0, n0);
            float den = den_analytic(xj);
            rp[j] = num * __builtin_amdgcn_rcpf(den + 1e-12f);
        }
        *reinterpret_cast<float4*>(&out[base]) = r;
    } else {
        for (int j = base; j < N; ++j) {
            float xj = x[j];
            float t = fminf(fmaxf(xj * scaleT, 0.0f), scaleT);
            int i0 = (int)t;
            if (i0 > TBL - 2) i0 = TBL - 2;
            float f = t - (float)i0;
            float num = fmaf(f, gnum[i0 + 1] - gnum[i0], gnum[i0]);
            float den = den_analytic(xj);
            out[j] = num * __builtin_amdgcn_rcpf(den + 1e-12f);
        }
    }
}

// Full subnet eval (fallback path only).
static __device__ __forceinline__ float subnet_eval_full(
    float xn,
    const float* __restrict__ w0, const float* __restrict__ bb0,
    const float* __restrict__ w1, const float* __restrict__ bb1,
    const float* __restrict__ w2, const float* __restrict__ bb2,
    const float* __restrict__ w3, float bb3)
{
    float h0[NW], h1[NW];
#pragma unroll
    for (int o = 0; o < NW; ++o) h0[o] = fast_tanh(fmaf(w0[o], xn, bb0[o]));
#pragma unroll
    for (int o = 0; o < NW; ++o) {
        float a = bb1[o];
        const float* row = &w1[o * NW];
#pragma unroll
        for (int j = 0; j < NW; ++j) a = fmaf(row[j], h0[j], a);
        h1[o] = fast_tanh(a);
    }
#pragma unroll
    for (int o = 0; o < NW; ++o) {
        float a = bb2[o];
        const float* row = &w2[o * NW];
#pragma unroll
        for (int j = 0; j < NW; ++j) a = fmaf(row[j], h1[j], a);
        h0[o] = fast_tanh(a);
    }
    float a = bb3;
#pragma unroll
    for (int j = 0; j < NW; ++j) a = fmaf(w3[j], h0[j], a);
    return a;
}

// Fallback if ws_size is tiny: direct evaluation (correct, slower).
__global__ void direct_eval(
    const float* __restrict__ x,
    const float* __restrict__ W0, const float* __restrict__ B0,
    const float* __restrict__ W1, const float* __restrict__ B1,
    const float* __restrict__ W2, const float* __restrict__ B2,
    const float* __restrict__ W3, const float* __restrict__ B3,
    float* __restrict__ out, int N)
{
    int n = blockIdx.x * blockDim.x + threadIdx.x;
    if (n >= N) return;
    float xv = x[n];
    float num = 0.f, den = 0.f;
    for (int k = 0; k < KSUB; ++k) {
        float w = window_w(xv, k);
        if (w <= 0.0f) continue;
        float center = ((float)k + 0.5f) * 0.0625f;
        float xn = (xv - center) * 10.958904109589041f;
        float o = subnet_eval_full(xn, &W0[k * NW], &B0[k * NW],
                                   &W1[k * NW * NW], &B1[k * NW],
                                   &W2[k * NW * NW], &B2[k * NW],
                                   &W3[k * NW], B3[k]);
        num += w * o;
        den += w;
    }
    out[n] = num * __builtin_amdgcn_rcpf(den + 1e-12f);
}

extern "C" void kernel_launch(void* const* d_in, const int* in_sizes, int n_in,
                              void* d_out, int out_size, void* d_ws, size_t ws_size,
                              hipStream_t stream) {
    const float* x  = (const float*)d_in[0];
    const float* W0 = (const float*)d_in[1];
    const float* B0 = (const float*)d_in[2];
    const float* W1 = (const float*)d_in[3];
    const float* B1 = (const float*)d_in[4];
    const float* W2 = (const float*)d_in[5];
    const float* B2 = (const float*)d_in[6];
    const float* W3 = (const float*)d_in[7];
    const float* B3 = (const float*)d_in[8];
    float* out = (float*)d_out;
    const int N = in_sizes[0];

    if ((size_t)TBL * 4 <= ws_size) {
        float* gnum = (float*)d_ws;
        build_tables<<<TBL / 64, BTHREADS, 0, stream>>>(
            W0, B0, W1, B1, W2, B2, W3, B3, gnum);
        int nv = (N + 3) / 4;
        eval_lerp<<<(nv + 255) / 256, 256, 0, stream>>>(x, gnum, out, N);
    } else {
        direct_eval<<<(N + 255) / 256, 256, 0, stream>>>(
            x, W0, B0, W1, B1, W2, B2, W3, B3, out, N);
    }
}